// Round 3
// baseline (115.040 us; speedup 1.0000x reference)
//
#include <hip/hip_runtime.h>

// Chamfer distance, B=16 clouds x N=4096 points x D=3, fp32.
// total = (1/(B*N)) * [ sum_i min_j d(x_i,Y) + sum_j min_i d(y_j,X) ]
// d = x^2 + y^2 - 2 x.y; x^2 is constant per query so we track
// min_j (y^2 + (-2x).y) and add x^2 at the end.
// Inner loop: 3 fma + 0.5 min3 per pair; KX=8 queries/thread so one
// ds_read_b128 serves 8 pairs (LDS pipe was the R2 bottleneck @ ~12cyc/instr).

namespace {

constexpr int kB = 16;
constexpr int kN = 4096;
constexpr int kNTH = 256;                 // threads per block
constexpr int kTILE = 256;                // y points staged in LDS per tile
constexpr int kPlane = kB * kN;           // 65536 query points per direction
constexpr float kScale = 1.0f / (float)(kB * kN);

__global__ void init_out(float* out) { out[0] = 0.0f; }

// One block: KX x-points per thread (kNTH*KX queries), scans one y-slice.
// DIRECT=true (S==1): full min computed -> block-reduce sum -> atomicAdd.
// DIRECT=false: store per-(slice, query) partial min to `part`; also
// idempotently zero out[0] (all min blocks finish before reduce starts).
template <int KX, int S, bool DIRECT>
__global__ __launch_bounds__(kNTH) void chamfer_min(
    const float* __restrict__ pred, const float* __restrict__ targ,
    float* __restrict__ part, float* __restrict__ out) {
  __shared__ float4 ytile[kTILE];

  const int t = threadIdx.x;
  const int xb = blockIdx.x;          // x-block within cloud
  const int b = blockIdx.y;           // cloud
  const int z = blockIdx.z;           // dir * S + slice
  const int dir = z / S;
  const int slice = z % S;

  if constexpr (!DIRECT) {
    if (t == 0) out[0] = 0.0f;        // idempotent; reduce runs after
  }

  const float* __restrict__ X = dir ? targ : pred;
  const float* __restrict__ Y = dir ? pred : targ;

  float xpx[KX], xpy[KX], xpz[KX], x2[KX], mn[KX];
  const int ibase = b * kN + xb * (kNTH * KX) + t;
#pragma unroll
  for (int k = 0; k < KX; ++k) {
    const int i = ibase + k * kNTH;
    const float a = X[3 * i], c = X[3 * i + 1], d = X[3 * i + 2];
    x2[k] = fmaf(a, a, fmaf(c, c, d * d));
    xpx[k] = -2.0f * a; xpy[k] = -2.0f * c; xpz[k] = -2.0f * d;
    mn[k] = 1e30f;
  }

  constexpr int YSL = kN / S;               // y points this block scans
  const int ybase = b * kN + slice * YSL;
  for (int t0 = 0; t0 < YSL; t0 += kTILE) {
    const int j = ybase + t0 + t;
    const float a = Y[3 * j], c = Y[3 * j + 1], d = Y[3 * j + 2];
    __syncthreads();  // protect previous tile's readers
    ytile[t] = make_float4(a, c, d, fmaf(a, a, fmaf(c, c, d * d)));
    __syncthreads();
#pragma unroll 4
    for (int jj = 0; jj < kTILE; jj += 2) {
      const float4 q0 = ytile[jj];      // broadcast ds_read_b128
      const float4 q1 = ytile[jj + 1];
#pragma unroll
      for (int k = 0; k < KX; ++k) {
        const float v0 =
            fmaf(xpx[k], q0.x, fmaf(xpy[k], q0.y, fmaf(xpz[k], q0.z, q0.w)));
        const float v1 =
            fmaf(xpx[k], q1.x, fmaf(xpy[k], q1.y, fmaf(xpz[k], q1.z, q1.w)));
        mn[k] = fminf(mn[k], fminf(v0, v1));   // -> v_min3_f32
      }
    }
  }

  if constexpr (DIRECT) {
    float s = 0.0f;
#pragma unroll
    for (int k = 0; k < KX; ++k) s += x2[k] + mn[k];
    for (int o = 32; o > 0; o >>= 1) s += __shfl_down(s, o, 64);
    __shared__ float wsum[kNTH / 64];
    const int lane = t & 63, w = t >> 6;
    if (lane == 0) wsum[w] = s;
    __syncthreads();
    if (t == 0) {
      float tot = 0.0f;
#pragma unroll
      for (int w2 = 0; w2 < kNTH / 64; ++w2) tot += wsum[w2];
      atomicAdd(out, tot * kScale);
    }
  } else {
#pragma unroll
    for (int k = 0; k < KX; ++k)
      part[(size_t)z * kPlane + (ibase + k * kNTH)] = x2[k] + mn[k];
  }
}

// Min over S slices per query (RQ queries per thread), then global sum via
// one atomicAdd per block (64 blocks total).
template <int S, int RQ>
__global__ __launch_bounds__(256) void chamfer_reduce(
    const float* __restrict__ part, float* __restrict__ out) {
  float s = 0.0f;
#pragma unroll
  for (int r = 0; r < RQ; ++r) {
    const int u = blockIdx.x * (256 * RQ) + r * 256 + threadIdx.x;
    const int dir = u >> 16;                        // kPlane == 65536
    const int q = u & (kPlane - 1);
    float m = 1e30f;
#pragma unroll
    for (int sl = 0; sl < S; ++sl)
      m = fminf(m, part[(size_t)(dir * S + sl) * kPlane + q]);
    s += m;
  }
  for (int o = 32; o > 0; o >>= 1) s += __shfl_down(s, o, 64);
  __shared__ float wsum[4];
  const int lane = threadIdx.x & 63, w = threadIdx.x >> 6;
  if (lane == 0) wsum[w] = s;
  __syncthreads();
  if (threadIdx.x == 0)
    atomicAdd(out, (wsum[0] + wsum[1] + wsum[2] + wsum[3]) * kScale);
}

}  // namespace

extern "C" void kernel_launch(void* const* d_in, const int* in_sizes, int n_in,
                              void* d_out, int out_size, void* d_ws,
                              size_t ws_size, hipStream_t stream) {
  const float* pred = (const float*)d_in[0];
  const float* targ = (const float*)d_in[1];
  float* out = (float*)d_out;
  float* part = (float*)d_ws;

  constexpr int KX = 8;   // x-points/thread -> 1 LDS b128 read per 16 pairs
  constexpr int RQ = 8;   // queries per reduce thread -> 64 reduce blocks
  const size_t need16 = (size_t)2 * 16 * kPlane * sizeof(float);  // 8 MB
  const size_t need8 = (size_t)2 * 8 * kPlane * sizeof(float);    // 4 MB
  const size_t need4 = (size_t)2 * 4 * kPlane * sizeof(float);    // 2 MB
  if (ws_size >= need16) {
    constexpr int S = 16;  // 1024 blocks -> 4 blocks/CU, 16 waves/CU
    dim3 grid(kN / (kNTH * KX), kB, 2 * S);
    chamfer_min<KX, S, false><<<grid, kNTH, 0, stream>>>(pred, targ, part, out);
    chamfer_reduce<S, RQ>
        <<<dim3(2 * kPlane / (256 * RQ)), 256, 0, stream>>>(part, out);
  } else if (ws_size >= need8) {
    constexpr int S = 8;   // 512 blocks -> 2 blocks/CU
    dim3 grid(kN / (kNTH * KX), kB, 2 * S);
    chamfer_min<KX, S, false><<<grid, kNTH, 0, stream>>>(pred, targ, part, out);
    chamfer_reduce<S, RQ>
        <<<dim3(2 * kPlane / (256 * RQ)), 256, 0, stream>>>(part, out);
  } else if (ws_size >= need4) {
    constexpr int S = 4;
    dim3 grid(kN / (kNTH * KX), kB, 2 * S);
    chamfer_min<KX, S, false><<<grid, kNTH, 0, stream>>>(pred, targ, part, out);
    chamfer_reduce<S, RQ>
        <<<dim3(2 * kPlane / (256 * RQ)), 256, 0, stream>>>(part, out);
  } else {
    // Fallback: no workspace needed; fewer blocks but still correct.
    init_out<<<dim3(1), dim3(1), 0, stream>>>(out);
    constexpr int KX2 = 2;
    dim3 grid(kN / (kNTH * KX2), kB, 2);
    chamfer_min<KX2, 1, true><<<grid, kNTH, 0, stream>>>(pred, targ, nullptr,
                                                         out);
  }
}

// Round 4
// 109.010 us; speedup vs baseline: 1.0553x; 1.0553x over previous
//
#include <hip/hip_runtime.h>

// Chamfer distance, B=16 clouds x N=4096 points x D=3, fp32.
// total = (1/(B*N)) * [ sum_i min_j d(x_i,Y) + sum_j min_i d(y_j,X) ]
// d = x^2 + y^2 - 2 x.y; x^2 is constant per query so we track
// min_j (y^2 + (-2x).y) and add x^2 at the end.
// R4: inner loop in inline asm using only 2-VGPR-source ops (v_mov + v_fmac
// chains) to test the VOP3-3-src-half-rate theory (R2/R3 both pinned at the
// 4cyc/VOP3 model's 48 us despite halved LDS traffic).

namespace {

constexpr int kB = 16;
constexpr int kN = 4096;
constexpr int kNTH = 256;                 // threads per block
constexpr int kTILE = 256;                // y points staged in LDS per tile
constexpr int kPlane = kB * kN;           // 65536 query points per direction
constexpr float kScale = 1.0f / (float)(kB * kN);

__global__ void init_out(float* out) { out[0] = 0.0f; }

// One block: KX x-points per thread (kNTH*KX queries), scans one y-slice.
// DIRECT=true (S==1): full min computed -> block-reduce sum -> atomicAdd.
// DIRECT=false: store per-(slice, query) partial min to `part`; also
// idempotently zero out[0] (all min blocks finish before reduce starts).
template <int KX, int S, bool DIRECT>
__global__ __launch_bounds__(kNTH) void chamfer_min(
    const float* __restrict__ pred, const float* __restrict__ targ,
    float* __restrict__ part, float* __restrict__ out) {
  __shared__ float4 ytile[kTILE];

  const int t = threadIdx.x;
  const int xb = blockIdx.x;          // x-block within cloud
  const int b = blockIdx.y;           // cloud
  const int z = blockIdx.z;           // dir * S + slice
  const int dir = z / S;
  const int slice = z % S;

  if constexpr (!DIRECT) {
    if (t == 0) out[0] = 0.0f;        // idempotent; reduce runs after
  }

  const float* __restrict__ X = dir ? targ : pred;
  const float* __restrict__ Y = dir ? pred : targ;

  float xpx[KX], xpy[KX], xpz[KX], x2[KX], mn[KX];
  const int ibase = b * kN + xb * (kNTH * KX) + t;
#pragma unroll
  for (int k = 0; k < KX; ++k) {
    const int i = ibase + k * kNTH;
    const float a = X[3 * i], c = X[3 * i + 1], d = X[3 * i + 2];
    x2[k] = fmaf(a, a, fmaf(c, c, d * d));
    xpx[k] = -2.0f * a; xpy[k] = -2.0f * c; xpz[k] = -2.0f * d;
    mn[k] = 1e30f;
  }

  constexpr int YSL = kN / S;               // y points this block scans
  const int ybase = b * kN + slice * YSL;
  for (int t0 = 0; t0 < YSL; t0 += kTILE) {
    const int j = ybase + t0 + t;
    const float a = Y[3 * j], c = Y[3 * j + 1], d = Y[3 * j + 2];
    __syncthreads();  // protect previous tile's readers
    ytile[t] = make_float4(a, c, d, fmaf(a, a, fmaf(c, c, d * d)));
    __syncthreads();
#pragma unroll 4
    for (int jj = 0; jj < kTILE; jj += 2) {
      const float4 q0 = ytile[jj];      // broadcast ds_read_b128
      const float4 q1 = ytile[jj + 1];
#pragma unroll
      for (int k = 0; k < KX; ++k) {
        float v0, v1;
        // All 2-source VOP2 except the single min3. v0/v1 chains
        // interleaved so dependent fmacs are >=4 cycles apart.
        asm("v_mov_b32 %1, %3\n\t"
            "v_mov_b32 %2, %4\n\t"
            "v_fmac_f32 %1, %5, %6\n\t"
            "v_fmac_f32 %2, %5, %7\n\t"
            "v_fmac_f32 %1, %8, %9\n\t"
            "v_fmac_f32 %2, %8, %10\n\t"
            "v_fmac_f32 %1, %11, %12\n\t"
            "v_fmac_f32 %2, %11, %13\n\t"
            "v_min3_f32 %0, %0, %1, %2"
            : "+v"(mn[k]), "=&v"(v0), "=&v"(v1)
            : "v"(q0.w), "v"(q1.w),
              "v"(xpz[k]), "v"(q0.z), "v"(q1.z),
              "v"(xpy[k]), "v"(q0.y), "v"(q1.y),
              "v"(xpx[k]), "v"(q0.x), "v"(q1.x));
      }
    }
  }

  if constexpr (DIRECT) {
    float s = 0.0f;
#pragma unroll
    for (int k = 0; k < KX; ++k) s += x2[k] + mn[k];
    for (int o = 32; o > 0; o >>= 1) s += __shfl_down(s, o, 64);
    __shared__ float wsum[kNTH / 64];
    const int lane = t & 63, w = t >> 6;
    if (lane == 0) wsum[w] = s;
    __syncthreads();
    if (t == 0) {
      float tot = 0.0f;
#pragma unroll
      for (int w2 = 0; w2 < kNTH / 64; ++w2) tot += wsum[w2];
      atomicAdd(out, tot * kScale);
    }
  } else {
#pragma unroll
    for (int k = 0; k < KX; ++k)
      part[(size_t)z * kPlane + (ibase + k * kNTH)] = x2[k] + mn[k];
  }
}

// Min over S slices per query (RQ queries per thread), then global sum via
// one atomicAdd per block.
template <int S, int RQ>
__global__ __launch_bounds__(256) void chamfer_reduce(
    const float* __restrict__ part, float* __restrict__ out) {
  float s = 0.0f;
#pragma unroll
  for (int r = 0; r < RQ; ++r) {
    const int u = blockIdx.x * (256 * RQ) + r * 256 + threadIdx.x;
    const int dir = u >> 16;                        // kPlane == 65536
    const int q = u & (kPlane - 1);
    float m = 1e30f;
#pragma unroll
    for (int sl = 0; sl < S; ++sl)
      m = fminf(m, part[(size_t)(dir * S + sl) * kPlane + q]);
    s += m;
  }
  for (int o = 32; o > 0; o >>= 1) s += __shfl_down(s, o, 64);
  __shared__ float wsum[4];
  const int lane = threadIdx.x & 63, w = threadIdx.x >> 6;
  if (lane == 0) wsum[w] = s;
  __syncthreads();
  if (threadIdx.x == 0)
    atomicAdd(out, (wsum[0] + wsum[1] + wsum[2] + wsum[3]) * kScale);
}

}  // namespace

extern "C" void kernel_launch(void* const* d_in, const int* in_sizes, int n_in,
                              void* d_out, int out_size, void* d_ws,
                              size_t ws_size, hipStream_t stream) {
  const float* pred = (const float*)d_in[0];
  const float* targ = (const float*)d_in[1];
  float* out = (float*)d_out;
  float* part = (float*)d_ws;

  constexpr int KX = 8;   // x-points/thread -> 1 LDS b128 read per 16 pairs
  constexpr int RQ = 2;   // queries per reduce thread -> 256 reduce blocks
  const size_t need16 = (size_t)2 * 16 * kPlane * sizeof(float);  // 8 MB
  const size_t need8 = (size_t)2 * 8 * kPlane * sizeof(float);    // 4 MB
  const size_t need4 = (size_t)2 * 4 * kPlane * sizeof(float);    // 2 MB
  if (ws_size >= need16) {
    constexpr int S = 16;  // 1024 blocks -> 4 blocks/CU
    dim3 grid(kN / (kNTH * KX), kB, 2 * S);
    chamfer_min<KX, S, false><<<grid, kNTH, 0, stream>>>(pred, targ, part, out);
    chamfer_reduce<S, RQ>
        <<<dim3(2 * kPlane / (256 * RQ)), 256, 0, stream>>>(part, out);
  } else if (ws_size >= need8) {
    constexpr int S = 8;   // 512 blocks -> 2 blocks/CU
    dim3 grid(kN / (kNTH * KX), kB, 2 * S);
    chamfer_min<KX, S, false><<<grid, kNTH, 0, stream>>>(pred, targ, part, out);
    chamfer_reduce<S, RQ>
        <<<dim3(2 * kPlane / (256 * RQ)), 256, 0, stream>>>(part, out);
  } else if (ws_size >= need4) {
    constexpr int S = 4;
    dim3 grid(kN / (kNTH * KX), kB, 2 * S);
    chamfer_min<KX, S, false><<<grid, kNTH, 0, stream>>>(pred, targ, part, out);
    chamfer_reduce<S, RQ>
        <<<dim3(2 * kPlane / (256 * RQ)), 256, 0, stream>>>(part, out);
  } else {
    // Fallback: no workspace needed; fewer blocks but still correct.
    init_out<<<dim3(1), dim3(1), 0, stream>>>(out);
    constexpr int KX2 = 2;
    dim3 grid(kN / (kNTH * KX2), kB, 2);
    chamfer_min<KX2, 1, true><<<grid, kNTH, 0, stream>>>(pred, targ, nullptr,
                                                         out);
  }
}

// Round 5
// 101.311 us; speedup vs baseline: 1.1355x; 1.0760x over previous
//
#include <hip/hip_runtime.h>

// Chamfer distance, B=16 clouds x N=4096 points x D=3, fp32.
// total = (1/(B*N)) * [ sum_i min_j d(x_i,Y) + sum_j min_i d(y_j,X) ]
// d = x^2 + y^2 - 2 x.y; x^2 constant per query -> track min_j (y^2-2x.y).
// R5: packed fp32 (v_pk_fma_f32, VOP3P) processes 2 y-points per instr.
// LDS tile stored pair-SoA: tA[j]=(x0,x1,y0,y1), tB[j]=(z0,z1,w0,w1) so the
// two ds_read_b128 per 2-y yield component pairs as aligned VGPR pairs.
// Inner loop: 3 pk_fma + 1 min3 per (k, 2y) = 2.0 VALU instrs per pair.

namespace {

constexpr int kB = 16;
constexpr int kN = 4096;
constexpr int kNTH = 256;                 // threads per block
constexpr int kTILE = 256;                // y points staged in LDS per tile
constexpr int kPlane = kB * kN;           // 65536 query points per direction
constexpr float kScale = 1.0f / (float)(kB * kN);

__global__ void init_out(float* out) { out[0] = 0.0f; }

// One block: KX x-points per thread (kNTH*KX queries), scans one y-slice.
// DIRECT=true (S==1): full min computed -> block-reduce sum -> atomicAdd.
// DIRECT=false: store per-(slice, query) partial min to `part`; also
// idempotently zero out[0] (all min blocks finish before reduce starts).
template <int KX, int S, bool DIRECT>
__global__ __launch_bounds__(kNTH) void chamfer_min(
    const float* __restrict__ pred, const float* __restrict__ targ,
    float* __restrict__ part, float* __restrict__ out) {
  __shared__ float4 tA[kTILE / 2];   // (x_{2j}, x_{2j+1}, y_{2j}, y_{2j+1})
  __shared__ float4 tB[kTILE / 2];   // (z_{2j}, z_{2j+1}, w_{2j}, w_{2j+1})

  const int t = threadIdx.x;
  const int xb = blockIdx.x;          // x-block within cloud
  const int b = blockIdx.y;           // cloud
  const int z = blockIdx.z;           // dir * S + slice
  const int dir = z / S;
  const int slice = z % S;

  if constexpr (!DIRECT) {
    if (t == 0) out[0] = 0.0f;        // idempotent; reduce runs after
  }

  const float* __restrict__ X = dir ? targ : pred;
  const float* __restrict__ Y = dir ? pred : targ;

  // x components duplicated into both halves of a pair for pk_fma broadcast.
  float2 xx2[KX], xy2[KX], xz2[KX];
  float x2[KX], mn[KX];
  const int ibase = b * kN + xb * (kNTH * KX) + t;
#pragma unroll
  for (int k = 0; k < KX; ++k) {
    const int i = ibase + k * kNTH;
    const float a = X[3 * i], c = X[3 * i + 1], d = X[3 * i + 2];
    x2[k] = fmaf(a, a, fmaf(c, c, d * d));
    const float pa = -2.0f * a, pc = -2.0f * c, pd = -2.0f * d;
    xx2[k] = make_float2(pa, pa);
    xy2[k] = make_float2(pc, pc);
    xz2[k] = make_float2(pd, pd);
    mn[k] = 1e30f;
  }

  constexpr int YSL = kN / S;               // y points this block scans
  const int ybase = b * kN + slice * YSL;
  for (int t0 = 0; t0 < YSL; t0 += kTILE) {
    __syncthreads();  // protect previous tile's readers
    if (t < kTILE / 2) {                    // stage pair t: points 2t, 2t+1
      const int j0 = 3 * (ybase + t0 + 2 * t);
      const float a0 = Y[j0], c0 = Y[j0 + 1], d0 = Y[j0 + 2];
      const float a1 = Y[j0 + 3], c1 = Y[j0 + 4], d1 = Y[j0 + 5];
      tA[t] = make_float4(a0, a1, c0, c1);
      tB[t] = make_float4(d0, d1, fmaf(a0, a0, fmaf(c0, c0, d0 * d0)),
                          fmaf(a1, a1, fmaf(c1, c1, d1 * d1)));
    }
    __syncthreads();
#pragma unroll 2
    for (int jj = 0; jj < kTILE / 2; ++jj) {
      const float4 qa = tA[jj];       // broadcast ds_read_b128
      const float4 qb = tB[jj];
      const float2 qx = make_float2(qa.x, qa.y);
      const float2 qy = make_float2(qa.z, qa.w);
      const float2 qz = make_float2(qb.x, qb.y);
      const float2 qw = make_float2(qb.z, qb.w);
#pragma unroll
      for (int k = 0; k < KX; ++k) {
        float2 acc;
        asm("v_pk_fma_f32 %0, %1, %2, %3\n\t"
            "v_pk_fma_f32 %0, %4, %5, %0\n\t"
            "v_pk_fma_f32 %0, %6, %7, %0"
            : "=&v"(acc)
            : "v"(xz2[k]), "v"(qz), "v"(qw),
              "v"(xy2[k]), "v"(qy),
              "v"(xx2[k]), "v"(qx));
        asm("v_min3_f32 %0, %0, %1, %2"
            : "+v"(mn[k])
            : "v"(acc.x), "v"(acc.y));
      }
    }
  }

  if constexpr (DIRECT) {
    float s = 0.0f;
#pragma unroll
    for (int k = 0; k < KX; ++k) s += x2[k] + mn[k];
    for (int o = 32; o > 0; o >>= 1) s += __shfl_down(s, o, 64);
    __shared__ float wsum[kNTH / 64];
    const int lane = t & 63, w = t >> 6;
    if (lane == 0) wsum[w] = s;
    __syncthreads();
    if (t == 0) {
      float tot = 0.0f;
#pragma unroll
      for (int w2 = 0; w2 < kNTH / 64; ++w2) tot += wsum[w2];
      atomicAdd(out, tot * kScale);
    }
  } else {
#pragma unroll
    for (int k = 0; k < KX; ++k)
      part[(size_t)z * kPlane + (ibase + k * kNTH)] = x2[k] + mn[k];
  }
}

// Min over S slices per query (RQ queries per thread), then global sum via
// one atomicAdd per block.
template <int S, int RQ>
__global__ __launch_bounds__(256) void chamfer_reduce(
    const float* __restrict__ part, float* __restrict__ out) {
  float s = 0.0f;
#pragma unroll
  for (int r = 0; r < RQ; ++r) {
    const int u = blockIdx.x * (256 * RQ) + r * 256 + threadIdx.x;
    const int dir = u >> 16;                        // kPlane == 65536
    const int q = u & (kPlane - 1);
    float m = 1e30f;
#pragma unroll
    for (int sl = 0; sl < S; ++sl)
      m = fminf(m, part[(size_t)(dir * S + sl) * kPlane + q]);
    s += m;
  }
  for (int o = 32; o > 0; o >>= 1) s += __shfl_down(s, o, 64);
  __shared__ float wsum[4];
  const int lane = threadIdx.x & 63, w = threadIdx.x >> 6;
  if (lane == 0) wsum[w] = s;
  __syncthreads();
  if (threadIdx.x == 0)
    atomicAdd(out, (wsum[0] + wsum[1] + wsum[2] + wsum[3]) * kScale);
}

}  // namespace

extern "C" void kernel_launch(void* const* d_in, const int* in_sizes, int n_in,
                              void* d_out, int out_size, void* d_ws,
                              size_t ws_size, hipStream_t stream) {
  const float* pred = (const float*)d_in[0];
  const float* targ = (const float*)d_in[1];
  float* out = (float*)d_out;
  float* part = (float*)d_ws;

  constexpr int KX = 8;   // x-points/thread -> 1 LDS b128 read per 16 pairs
  constexpr int RQ = 2;   // queries per reduce thread -> 256 reduce blocks
  const size_t need16 = (size_t)2 * 16 * kPlane * sizeof(float);  // 8 MB
  const size_t need8 = (size_t)2 * 8 * kPlane * sizeof(float);    // 4 MB
  const size_t need4 = (size_t)2 * 4 * kPlane * sizeof(float);    // 2 MB
  if (ws_size >= need16) {
    constexpr int S = 16;  // 1024 blocks -> 4 blocks/CU
    dim3 grid(kN / (kNTH * KX), kB, 2 * S);
    chamfer_min<KX, S, false><<<grid, kNTH, 0, stream>>>(pred, targ, part, out);
    chamfer_reduce<S, RQ>
        <<<dim3(2 * kPlane / (256 * RQ)), 256, 0, stream>>>(part, out);
  } else if (ws_size >= need8) {
    constexpr int S = 8;   // 512 blocks -> 2 blocks/CU
    dim3 grid(kN / (kNTH * KX), kB, 2 * S);
    chamfer_min<KX, S, false><<<grid, kNTH, 0, stream>>>(pred, targ, part, out);
    chamfer_reduce<S, RQ>
        <<<dim3(2 * kPlane / (256 * RQ)), 256, 0, stream>>>(part, out);
  } else if (ws_size >= need4) {
    constexpr int S = 4;
    dim3 grid(kN / (kNTH * KX), kB, 2 * S);
    chamfer_min<KX, S, false><<<grid, kNTH, 0, stream>>>(pred, targ, part, out);
    chamfer_reduce<S, RQ>
        <<<dim3(2 * kPlane / (256 * RQ)), 256, 0, stream>>>(part, out);
  } else {
    // Fallback: no workspace needed; fewer blocks but still correct.
    init_out<<<dim3(1), dim3(1), 0, stream>>>(out);
    constexpr int KX2 = 2;
    dim3 grid(kN / (kNTH * KX2), kB, 2);
    chamfer_min<KX2, 1, true><<<grid, kNTH, 0, stream>>>(pred, targ, nullptr,
                                                         out);
  }
}